// Round 1
// baseline (293.518 us; speedup 1.0000x reference)
//
#include <hip/hip_runtime.h>
#include <stdint.h>

#define B_ 2
#define S_ 2048
#define H_ 1024
#define NH_ 16
#define DK_ 64
#define M_ (B_*S_)
#define LOG2E 1.4426950408889634f

typedef __attribute__((ext_vector_type(8))) short short8;
typedef __attribute__((ext_vector_type(4))) float f32x4;

#define GLDS16(g, s) __builtin_amdgcn_global_load_lds( \
    (const __attribute__((address_space(1))) unsigned int*)(g), \
    (__attribute__((address_space(3))) unsigned int*)(s), 16, 0, 0)

__device__ __forceinline__ unsigned short f2bf(float x) {
  union { float f; unsigned u; } c; c.f = x;
  unsigned r = (c.u + 0x7FFF + ((c.u >> 16) & 1)) >> 16;
  return (unsigned short)r;
}

// ---------------- fp32 -> bf16 converts ----------------
__global__ void k_cvt3(const float4* __restrict__ a, const float4* __restrict__ b,
                       const float4* __restrict__ c,
                       ushort4* __restrict__ oa, ushort4* __restrict__ ob,
                       ushort4* __restrict__ oc) {
  int idx = blockIdx.x * 256 + threadIdx.x;      // 3 * 2^20
  int t = idx >> 20, i = idx & ((1 << 20) - 1);
  const float4* s = (t == 0) ? a : (t == 1) ? b : c;
  ushort4* o = (t == 0) ? oa : (t == 1) ? ob : oc;
  float4 v = s[i];
  ushort4 r; r.x = f2bf(v.x); r.y = f2bf(v.y); r.z = f2bf(v.z); r.w = f2bf(v.w);
  o[i] = r;
}

__global__ void k_cvtw(const float4* __restrict__ a, const float4* __restrict__ b,
                       const float4* __restrict__ c, const float4* __restrict__ d,
                       ushort4* __restrict__ oa, ushort4* __restrict__ ob,
                       ushort4* __restrict__ oc, ushort4* __restrict__ od) {
  int idx = blockIdx.x * 256 + threadIdx.x;      // 4 * 2^18
  int t = idx >> 18, i = idx & ((1 << 18) - 1);
  const float4* s = (t == 0) ? a : (t == 1) ? b : (t == 2) ? c : d;
  ushort4* o = (t == 0) ? oa : (t == 1) ? ob : (t == 2) ? oc : od;
  float4 v = s[i];
  ushort4 r; r.x = f2bf(v.x); r.y = f2bf(v.y); r.z = f2bf(v.z); r.w = f2bf(v.w);
  o[i] = r;
}

// ---------------- GEMM: C = A(MxK) * Bw(NxK)^T + bias, K=1024 ----------------
enum { MODE_BF16 = 0, MODE_VT = 1, MODE_F32 = 2 };

__device__ __forceinline__ void gemm_body(
    const unsigned short* __restrict__ A, const unsigned short* __restrict__ Bw,
    const float* __restrict__ bias, void* __restrict__ Cout, int mode,
    int bx, int by) {
  __shared__ unsigned short As[128 * 64];   // [row][64], XOR-swizzled 16B chunks
  __shared__ unsigned short Bs[128 * 64];
  const int tid = threadIdx.x;
  const int w = tid >> 6, lane = tid & 63;
  const int lr = lane & 15, hi = lane >> 4;
  const int wr = w >> 1, wc = w & 1;
  const int m0 = by * 128, n0 = bx * 128;

  f32x4 acc[4][4];
#pragma unroll
  for (int i = 0; i < 4; i++)
#pragma unroll
    for (int j = 0; j < 4; j++) acc[i][j] = (f32x4){0.f, 0.f, 0.f, 0.f};

  for (int k0 = 0; k0 < H_; k0 += 64) {
    __syncthreads();
#pragma unroll
    for (int it = 0; it < 4; ++it) {
      int c = it * 256 + tid;
      int row = c >> 3, ch = c & 7;
      const unsigned short* ga = A + (size_t)(m0 + row) * H_ + k0 + ((ch ^ (row & 7)) << 3);
      GLDS16(ga, As + (it * 256 + w * 64) * 8);
      const unsigned short* gb = Bw + (size_t)(n0 + row) * H_ + k0 + ((ch ^ (row & 7)) << 3);
      GLDS16(gb, Bs + (it * 256 + w * 64) * 8);
    }
    __syncthreads();
#pragma unroll
    for (int ks = 0; ks < 2; ++ks) {
      short8 af[4], bfg[4];
#pragma unroll
      for (int mi = 0; mi < 4; ++mi) {
        int row = wr * 64 + mi * 16 + lr;
        int ch = ((ks << 2) | hi) ^ (lr & 7);
        af[mi] = *(const short8*)((const char*)As + row * 128 + (ch << 4));
      }
#pragma unroll
      for (int ni = 0; ni < 4; ++ni) {
        int row = wc * 64 + ni * 16 + lr;
        int ch = ((ks << 2) | hi) ^ (lr & 7);
        bfg[ni] = *(const short8*)((const char*)Bs + row * 128 + (ch << 4));
      }
#pragma unroll
      for (int mi = 0; mi < 4; ++mi)
#pragma unroll
        for (int ni = 0; ni < 4; ++ni)
          acc[mi][ni] = __builtin_amdgcn_mfma_f32_16x16x32_bf16(af[mi], bfg[ni], acc[mi][ni], 0, 0, 0);
    }
  }

  float bvv[4];
#pragma unroll
  for (int ni = 0; ni < 4; ++ni) bvv[ni] = bias[n0 + wc * 64 + ni * 16 + lr];

  if (mode == MODE_BF16) {
    unsigned short* C = (unsigned short*)Cout;
#pragma unroll
    for (int mi = 0; mi < 4; ++mi)
#pragma unroll
      for (int ni = 0; ni < 4; ++ni) {
        int col = n0 + wc * 64 + ni * 16 + lr;
#pragma unroll
        for (int j = 0; j < 4; ++j) {
          int r = m0 + wr * 64 + mi * 16 + hi * 4 + j;
          C[(size_t)r * H_ + col] = f2bf(acc[mi][ni][j] + bvv[ni]);
        }
      }
  } else if (mode == MODE_F32) {
    float* C = (float*)Cout;
#pragma unroll
    for (int mi = 0; mi < 4; ++mi)
#pragma unroll
      for (int ni = 0; ni < 4; ++ni) {
        int col = n0 + wc * 64 + ni * 16 + lr;
#pragma unroll
        for (int j = 0; j < 4; ++j) {
          int r = m0 + wr * 64 + mi * 16 + hi * 4 + j;
          C[(size_t)r * H_ + col] = acc[mi][ni][j] + bvv[ni];
        }
      }
  } else {  // MODE_VT: Vt[(b*H + col)][s] = v, packed 4 bf16 along s
    unsigned short* Vt = (unsigned short*)Cout;
#pragma unroll
    for (int mi = 0; mi < 4; ++mi) {
      int rbase = m0 + wr * 64 + mi * 16 + hi * 4;
      int bb = rbase >> 11, s0 = rbase & (S_ - 1);
#pragma unroll
      for (int ni = 0; ni < 4; ++ni) {
        int col = n0 + wc * 64 + ni * 16 + lr;
        ushort4 pk;
        pk.x = f2bf(acc[mi][ni][0] + bvv[ni]);
        pk.y = f2bf(acc[mi][ni][1] + bvv[ni]);
        pk.z = f2bf(acc[mi][ni][2] + bvv[ni]);
        pk.w = f2bf(acc[mi][ni][3] + bvv[ni]);
        *(ushort4*)(Vt + (size_t)(bb * H_ + col) * S_ + s0) = pk;
      }
    }
  }
}

__global__ __launch_bounds__(256, 2) void k_gemm_qkv(
    const unsigned short* __restrict__ Xq, const unsigned short* __restrict__ Xk,
    const unsigned short* __restrict__ Xv,
    const unsigned short* __restrict__ Wqb, const unsigned short* __restrict__ Wkb,
    const unsigned short* __restrict__ Wvb,
    const float* __restrict__ bq, const float* __restrict__ bk,
    const float* __restrict__ bv,
    unsigned short* __restrict__ Qb, unsigned short* __restrict__ Kb,
    unsigned short* __restrict__ Vtb) {
  int z = blockIdx.z;
  const unsigned short* A = (z == 0) ? Xq : (z == 1) ? Xk : Xv;
  const unsigned short* W = (z == 0) ? Wqb : (z == 1) ? Wkb : Wvb;
  const float* bias = (z == 0) ? bq : (z == 1) ? bk : bv;
  void* C = (z == 0) ? (void*)Qb : (z == 1) ? (void*)Kb : (void*)Vtb;
  gemm_body(A, W, bias, C, (z == 2) ? MODE_VT : MODE_BF16, blockIdx.x, blockIdx.y);
}

__global__ __launch_bounds__(256, 2) void k_gemm_o(
    const unsigned short* __restrict__ Ctx, const unsigned short* __restrict__ Wob,
    const float* __restrict__ bo, float* __restrict__ out) {
  gemm_body(Ctx, Wob, bo, (void*)out, MODE_F32, blockIdx.x, blockIdx.y);
}

// ---------------- flash attention ----------------
// grid 1024 blocks: (b, h, qtile of 64). 4 waves x 16 q-rows. KVBLK=128.
__global__ __launch_bounds__(256, 2) void k_attn(
    const unsigned short* __restrict__ Qb, const unsigned short* __restrict__ Kb,
    const unsigned short* __restrict__ Vtb, const int* __restrict__ amask,
    unsigned short* __restrict__ Ctx) {
  __shared__ unsigned short Klds[128 * 64];    // [key][d] swizzled
  __shared__ unsigned short Vtlds[64 * 128];   // [d][key] swizzled
  __shared__ unsigned short Plds[4][16 * 128]; // per-wave [q][key] swizzled
  __shared__ int mlds[S_];

  const int tid = threadIdx.x;
  const int w = tid >> 6, lane = tid & 63;
  const int lr = lane & 15, hi = lane >> 4;
  int bid = (blockIdx.x & 7) * 128 + (blockIdx.x >> 3);  // XCD-chunked swizzle
  const int qt = bid & 31;
  const int h = (bid >> 5) & 15;
  const int b = bid >> 9;
  const int q0 = qt * 64 + w * 16;

  for (int i = tid; i < S_ / 4; i += 256)
    ((int4*)mlds)[i] = ((const int4*)(amask + b * S_))[i];

  short8 aq[2];
  {
    const unsigned short* qp = Qb + (size_t)(b * S_ + q0 + lr) * H_ + h * DK_ + hi * 8;
    aq[0] = *(const short8*)qp;
    aq[1] = *(const short8*)(qp + 32);
  }

  f32x4 ctx[4];
#pragma unroll
  for (int nf = 0; nf < 4; ++nf) ctx[nf] = (f32x4){0.f, 0.f, 0.f, 0.f};
  float mrun[4], lrun[4];
#pragma unroll
  for (int j = 0; j < 4; ++j) { mrun[j] = -1e30f; lrun[j] = 0.f; }

  char* Pw = (char*)Plds[w];

  for (int kv0 = 0; kv0 < S_; kv0 += 128) {
    __syncthreads();
#pragma unroll
    for (int it = 0; it < 4; ++it) {
      int c = it * 256 + tid;
      int row = c >> 3, ch = c & 7;
      const unsigned short* g =
          Kb + (size_t)(b * S_ + kv0 + row) * H_ + h * DK_ + ((ch ^ (row & 7)) << 3);
      GLDS16(g, Klds + (it * 256 + w * 64) * 8);
      int rowv = c >> 4, chv = c & 15;
      const unsigned short* gv =
          Vtb + (size_t)(b * H_ + h * DK_ + rowv) * S_ + kv0 + ((chv ^ (rowv & 7)) << 3);
      GLDS16(gv, Vtlds + (it * 256 + w * 64) * 8);
    }
    __syncthreads();

    int mk[8];
#pragma unroll
    for (int n = 0; n < 8; ++n) mk[n] = mlds[kv0 + lr + 16 * n];

    f32x4 sc[8];
#pragma unroll
    for (int n = 0; n < 8; ++n) {
      sc[n] = (f32x4){0.f, 0.f, 0.f, 0.f};
      int key = lr + 16 * n;
#pragma unroll
      for (int ks = 0; ks < 2; ++ks) {
        int ch = ((ks << 2) | hi) ^ (key & 7);
        short8 bk = *(const short8*)((const char*)Klds + key * 128 + (ch << 4));
        sc[n] = __builtin_amdgcn_mfma_f32_16x16x32_bf16(aq[ks], bk, sc[n], 0, 0, 0);
      }
    }

    float csc[4];
#pragma unroll
    for (int j = 0; j < 4; ++j) {
      float sj[8]; float mx = -1e30f;
#pragma unroll
      for (int n = 0; n < 8; ++n) {
        float v = sc[n][j] * 0.125f;
        if (mk[n] == 0) v = 1e-9f;
        sj[n] = v; mx = fmaxf(mx, v);
      }
      mx = fmaxf(mx, __shfl_xor(mx, 1));
      mx = fmaxf(mx, __shfl_xor(mx, 2));
      mx = fmaxf(mx, __shfl_xor(mx, 4));
      mx = fmaxf(mx, __shfl_xor(mx, 8));
      float mnew = fmaxf(mrun[j], mx);
      float scale = exp2f((mrun[j] - mnew) * LOG2E);
      int ql = hi * 4 + j;
      float psum = 0.f;
#pragma unroll
      for (int n = 0; n < 8; ++n) {
        float p = exp2f((sj[n] - mnew) * LOG2E);
        psum += p;
        int key = lr + 16 * n;
        *(unsigned short*)(Pw + ql * 256 + (((key >> 3) ^ (ql & 7)) << 4) + (key & 7) * 2) = f2bf(p);
      }
      psum += __shfl_xor(psum, 1);
      psum += __shfl_xor(psum, 2);
      psum += __shfl_xor(psum, 4);
      psum += __shfl_xor(psum, 8);
      lrun[j] = lrun[j] * scale + psum;
      mrun[j] = mnew;
      csc[j] = scale;
    }
#pragma unroll
    for (int nf = 0; nf < 4; ++nf)
#pragma unroll
      for (int j = 0; j < 4; ++j) ctx[nf][j] *= csc[j];

#pragma unroll
    for (int ks = 0; ks < 4; ++ks) {
      int ch = ks * 4 + hi;
      short8 pa = *(const short8*)(Pw + lr * 256 + ((ch ^ (lr & 7)) << 4));
#pragma unroll
      for (int nf = 0; nf < 4; ++nf) {
        int d = lr + 16 * nf;
        short8 bv = *(const short8*)((const char*)Vtlds + d * 256 + ((ch ^ (d & 7)) << 4));
        ctx[nf] = __builtin_amdgcn_mfma_f32_16x16x32_bf16(pa, bv, ctx[nf], 0, 0, 0);
      }
    }
  }

#pragma unroll
  for (int j = 0; j < 4; ++j) {
    float inv = 1.0f / lrun[j];
#pragma unroll
    for (int nf = 0; nf < 4; ++nf) {
      float v = ctx[nf][j] * inv;
      Ctx[(size_t)(b * S_ + q0 + hi * 4 + j) * H_ + h * DK_ + lr + 16 * nf] = f2bf(v);
    }
  }
}

// ---------------- launch ----------------
extern "C" void kernel_launch(void* const* d_in, const int* in_sizes, int n_in,
                              void* d_out, int out_size, void* d_ws, size_t ws_size,
                              hipStream_t stream) {
  (void)in_sizes; (void)n_in; (void)out_size; (void)ws_size;
  const float* query = (const float*)d_in[0];
  const float* key   = (const float*)d_in[1];
  const float* value = (const float*)d_in[2];
  const int*   amask = (const int*)d_in[3];
  const float* Wq = (const float*)d_in[4];
  const float* bq = (const float*)d_in[5];
  const float* Wk = (const float*)d_in[6];
  const float* bk = (const float*)d_in[7];
  const float* Wv = (const float*)d_in[8];
  const float* bv = (const float*)d_in[9];
  const float* Wo = (const float*)d_in[10];
  const float* bo = (const float*)d_in[11];
  float* out = (float*)d_out;

  unsigned short* ws = (unsigned short*)d_ws;
  const size_t SZX = (size_t)M_ * H_;       // 4194304
  const size_t SZW = (size_t)H_ * H_;       // 1048576
  unsigned short* Xq  = ws;
  unsigned short* Xk  = Xq + SZX;
  unsigned short* Xv  = Xk + SZX;
  unsigned short* Wqb = Xv + SZX;
  unsigned short* Wkb = Wqb + SZW;
  unsigned short* Wvb = Wkb + SZW;
  unsigned short* Wob = Wvb + SZW;
  unsigned short* Qb  = Wob + SZW;
  unsigned short* Kb  = Qb + SZX;
  unsigned short* Vtb = Kb + SZX;
  unsigned short* Ctx = Vtb + SZX;

  k_cvt3<<<dim3(12288), dim3(256), 0, stream>>>(
      (const float4*)query, (const float4*)key, (const float4*)value,
      (ushort4*)Xq, (ushort4*)Xk, (ushort4*)Xv);
  k_cvtw<<<dim3(4096), dim3(256), 0, stream>>>(
      (const float4*)Wq, (const float4*)Wk, (const float4*)Wv, (const float4*)Wo,
      (ushort4*)Wqb, (ushort4*)Wkb, (ushort4*)Wvb, (ushort4*)Wob);
  k_gemm_qkv<<<dim3(8, 32, 3), dim3(256), 0, stream>>>(
      Xq, Xk, Xv, Wqb, Wkb, Wvb, bq, bk, bv, Qb, Kb, Vtb);
  k_attn<<<dim3(1024), dim3(256), 0, stream>>>(Qb, Kb, Vtb, amask, Ctx);
  k_gemm_o<<<dim3(8, 32), dim3(256), 0, stream>>>(Ctx, Wob, bo, out);
}

// Round 5
// 231.045 us; speedup vs baseline: 1.2704x; 1.2704x over previous
//
#include <hip/hip_runtime.h>
#include <stdint.h>

#define B_ 2
#define S_ 2048
#define H_ 1024
#define NH_ 16
#define DK_ 64
#define M_ (B_*S_)

typedef __attribute__((ext_vector_type(8))) short short8;
typedef __attribute__((ext_vector_type(4))) float f32x4;
typedef __attribute__((ext_vector_type(4))) unsigned u32x4;

#define GLDS16(g, s) __builtin_amdgcn_global_load_lds( \
    (const __attribute__((address_space(1))) unsigned int*)(g), \
    (__attribute__((address_space(3))) unsigned int*)(s), 16, 0, 0)

__device__ __forceinline__ unsigned short f2bf(float x) {
  union { float f; unsigned u; } c; c.f = x;
  unsigned r = (c.u + 0x7FFF + ((c.u >> 16) & 1)) >> 16;
  return (unsigned short)r;
}

__device__ __forceinline__ f32x4 vmax4(f32x4 a, f32x4 b) {
  f32x4 r;
  r[0] = fmaxf(a[0], b[0]); r[1] = fmaxf(a[1], b[1]);
  r[2] = fmaxf(a[2], b[2]); r[3] = fmaxf(a[3], b[3]);
  return r;
}

// ---------------- fp32 -> bf16 converts ----------------
__global__ void k_cvt3(const float4* __restrict__ a, const float4* __restrict__ b,
                       const float4* __restrict__ c,
                       ushort4* __restrict__ oa, ushort4* __restrict__ ob,
                       ushort4* __restrict__ oc) {
  int idx = blockIdx.x * 256 + threadIdx.x;      // 3 * 2^20
  int t = idx >> 20, i = idx & ((1 << 20) - 1);
  const float4* s = (t == 0) ? a : (t == 1) ? b : c;
  ushort4* o = (t == 0) ? oa : (t == 1) ? ob : oc;
  float4 v = s[i];
  ushort4 r; r.x = f2bf(v.x); r.y = f2bf(v.y); r.z = f2bf(v.z); r.w = f2bf(v.w);
  o[i] = r;
}

__global__ void k_cvtw(const float4* __restrict__ a, const float4* __restrict__ b,
                       const float4* __restrict__ c, const float4* __restrict__ d,
                       ushort4* __restrict__ oa, ushort4* __restrict__ ob,
                       ushort4* __restrict__ oc, ushort4* __restrict__ od) {
  int idx = blockIdx.x * 256 + threadIdx.x;      // 4 * 2^18
  int t = idx >> 18, i = idx & ((1 << 18) - 1);
  const float4* s = (t == 0) ? a : (t == 1) ? b : (t == 2) ? c : d;
  ushort4* o = (t == 0) ? oa : (t == 1) ? ob : (t == 2) ? oc : od;
  float4 v = s[i];
  ushort4 r; r.x = f2bf(v.x); r.y = f2bf(v.y); r.z = f2bf(v.z); r.w = f2bf(v.w);
  o[i] = r;
}

// ---------------- GEMM: C = A(MxK) * Bw(NxK)^T + bias, K=1024 ----------------
enum { MODE_Q = 0, MODE_K = 1, MODE_VT = 2, MODE_F32 = 3 };

__device__ __forceinline__ void gemm_body(
    const unsigned short* __restrict__ A, const unsigned short* __restrict__ Bw,
    const float* __restrict__ bias, const int* __restrict__ amask,
    void* __restrict__ Cout, int mode, int bx, int by) {
  __shared__ unsigned short As[128 * 64];   // [row][64], XOR-swizzled 16B chunks
  __shared__ unsigned short Bs[128 * 64];
  const int tid = threadIdx.x;
  const int w = tid >> 6, lane = tid & 63;
  const int lr = lane & 15, hi = lane >> 4;
  const int wr = w >> 1, wc = w & 1;
  const int m0 = by * 128, n0 = bx * 128;

  f32x4 acc[4][4];
#pragma unroll
  for (int i = 0; i < 4; i++)
#pragma unroll
    for (int j = 0; j < 4; j++) acc[i][j] = (f32x4){0.f, 0.f, 0.f, 0.f};

  for (int k0 = 0; k0 < H_; k0 += 64) {
    __syncthreads();
#pragma unroll
    for (int it = 0; it < 4; ++it) {
      int c = it * 256 + tid;
      int row = c >> 3, ch = c & 7;
      const unsigned short* ga = A + (size_t)(m0 + row) * H_ + k0 + ((ch ^ (row & 7)) << 3);
      GLDS16(ga, As + (it * 256 + w * 64) * 8);
      const unsigned short* gb = Bw + (size_t)(n0 + row) * H_ + k0 + ((ch ^ (row & 7)) << 3);
      GLDS16(gb, Bs + (it * 256 + w * 64) * 8);
    }
    __syncthreads();
#pragma unroll
    for (int ks = 0; ks < 2; ++ks) {
      short8 af[4], bfg[4];
#pragma unroll
      for (int mi = 0; mi < 4; ++mi) {
        int row = wr * 64 + mi * 16 + lr;
        int ch = ((ks << 2) | hi) ^ (lr & 7);
        af[mi] = *(const short8*)((const char*)As + row * 128 + (ch << 4));
      }
#pragma unroll
      for (int ni = 0; ni < 4; ++ni) {
        int row = wc * 64 + ni * 16 + lr;
        int ch = ((ks << 2) | hi) ^ (lr & 7);
        bfg[ni] = *(const short8*)((const char*)Bs + row * 128 + (ch << 4));
      }
#pragma unroll
      for (int mi = 0; mi < 4; ++mi)
#pragma unroll
        for (int ni = 0; ni < 4; ++ni)
          acc[mi][ni] = __builtin_amdgcn_mfma_f32_16x16x32_bf16(af[mi], bfg[ni], acc[mi][ni], 0, 0, 0);
    }
  }

  float bvv[4];
#pragma unroll
  for (int ni = 0; ni < 4; ++ni) bvv[ni] = bias[n0 + wc * 64 + ni * 16 + lr];

  if (mode == MODE_Q || mode == MODE_K) {
    unsigned short* C = (unsigned short*)Cout;
    float km[4][4];
    if (mode == MODE_K) {
#pragma unroll
      for (int mi = 0; mi < 4; ++mi)
#pragma unroll
        for (int j = 0; j < 4; ++j) {
          int r = m0 + wr * 64 + mi * 16 + hi * 4 + j;
          km[mi][j] = amask[r] ? 1.0f : 0.0f;
        }
    }
#pragma unroll
    for (int mi = 0; mi < 4; ++mi)
#pragma unroll
      for (int ni = 0; ni < 4; ++ni) {
        int col = n0 + wc * 64 + ni * 16 + lr;
#pragma unroll
        for (int j = 0; j < 4; ++j) {
          int r = m0 + wr * 64 + mi * 16 + hi * 4 + j;
          float v = acc[mi][ni][j] + bvv[ni];
          v *= (mode == MODE_Q) ? 0.125f : km[mi][j];
          C[(size_t)r * H_ + col] = f2bf(v);
        }
      }
  } else if (mode == MODE_F32) {
    float* C = (float*)Cout;
#pragma unroll
    for (int mi = 0; mi < 4; ++mi)
#pragma unroll
      for (int ni = 0; ni < 4; ++ni) {
        int col = n0 + wc * 64 + ni * 16 + lr;
#pragma unroll
        for (int j = 0; j < 4; ++j) {
          int r = m0 + wr * 64 + mi * 16 + hi * 4 + j;
          C[(size_t)r * H_ + col] = acc[mi][ni][j] + bvv[ni];
        }
      }
  } else {  // MODE_VT: Vt[(b*H + col)][s] = v, packed 4 bf16 along s
    unsigned short* Vt = (unsigned short*)Cout;
#pragma unroll
    for (int mi = 0; mi < 4; ++mi) {
      int rbase = m0 + wr * 64 + mi * 16 + hi * 4;
      int bb = rbase >> 11, s0 = rbase & (S_ - 1);
#pragma unroll
      for (int ni = 0; ni < 4; ++ni) {
        int col = n0 + wc * 64 + ni * 16 + lr;
        ushort4 pk;
        pk.x = f2bf(acc[mi][ni][0] + bvv[ni]);
        pk.y = f2bf(acc[mi][ni][1] + bvv[ni]);
        pk.z = f2bf(acc[mi][ni][2] + bvv[ni]);
        pk.w = f2bf(acc[mi][ni][3] + bvv[ni]);
        *(ushort4*)(Vt + (size_t)(bb * H_ + col) * S_ + s0) = pk;
      }
    }
  }
}

__global__ __launch_bounds__(256, 2) void k_gemm_qkv(
    const unsigned short* __restrict__ Xq, const unsigned short* __restrict__ Xk,
    const unsigned short* __restrict__ Xv,
    const unsigned short* __restrict__ Wqb, const unsigned short* __restrict__ Wkb,
    const unsigned short* __restrict__ Wvb,
    const float* __restrict__ bq, const float* __restrict__ bk,
    const float* __restrict__ bv, const int* __restrict__ amask,
    unsigned short* __restrict__ Qb, unsigned short* __restrict__ Kb,
    unsigned short* __restrict__ Vtb) {
  int z = blockIdx.z;
  const unsigned short* A = (z == 0) ? Xq : (z == 1) ? Xk : Xv;
  const unsigned short* W = (z == 0) ? Wqb : (z == 1) ? Wkb : Wvb;
  const float* bias = (z == 0) ? bq : (z == 1) ? bk : bv;
  void* C = (z == 0) ? (void*)Qb : (z == 1) ? (void*)Kb : (void*)Vtb;
  int mode = (z == 0) ? MODE_Q : (z == 1) ? MODE_K : MODE_VT;
  gemm_body(A, W, bias, amask, C, mode, blockIdx.x, blockIdx.y);
}

__global__ __launch_bounds__(256, 2) void k_gemm_o(
    const unsigned short* __restrict__ Ctx, const unsigned short* __restrict__ Wob,
    const float* __restrict__ bo, float* __restrict__ out) {
  gemm_body(Ctx, Wob, bo, nullptr, (void*)out, MODE_F32, blockIdx.x, blockIdx.y);
}

// ---------------- flash attention (swapped QK^T, in-register P) ----------------
// grid 1024 blocks: (b, h, qtile of 64). 4 waves x 16 q-rows. KVBLK=128.
// Q pre-scaled by 0.125; masked K rows zeroed (both in GEMM epilogues).
// Key interleave: sc[2m+p] holds keys 32m+8hi+4p+j at C-row 4hi+j, so the PV
// B-fragment (k=8hi+t for 16x16x32) is LANE-LOCAL: keys 32m+8hi+0..7 =
// (sc[2m][0..3], sc[2m+1][0..3]). Only the proven 16x16x32 builtin is used.
__global__ __launch_bounds__(256, 3) void k_attn(
    const unsigned short* __restrict__ Qb, const unsigned short* __restrict__ Kb,
    const unsigned short* __restrict__ Vtb, unsigned short* __restrict__ Ctx) {
  __shared__ unsigned short Klds[128 * 64];    // [key][d] 16B-chunk XOR swizzle
  __shared__ unsigned short Vtl[4 * 64 * 32];  // [m][d][32 keys], chunk-swizzled

  const int tid = threadIdx.x;
  const int w = tid >> 6, lane = tid & 63;
  const int lr = lane & 15, hi = lane >> 4;
  int bid = (blockIdx.x & 7) * 128 + (blockIdx.x >> 3);  // XCD-chunked swizzle
  const int qt = bid & 31;
  const int h = (bid >> 5) & 15;
  const int b = bid >> 9;
  const int q0 = qt * 64 + w * 16;

  // Q fragment (B operand: col=q=lr, k = ks*32 + hi*8 + t)
  short8 aq[2];
  {
    const unsigned short* qp = Qb + (size_t)(b * S_ + q0 + lr) * H_ + h * DK_ + hi * 8;
    aq[0] = *(const short8*)qp;
    aq[1] = *(const short8*)(qp + 32);
  }

  // A-row addresses for interleaved key mapping (p=0,1)
  const int krow0 = 8 * (lr >> 2) + (lr & 3);

  // per-thread staging source pointers (advance per kv-tile)
  const unsigned short* ksrc[4];
  const unsigned short* vsrc[4];
#pragma unroll
  for (int it = 0; it < 4; ++it) {
    int c = it * 256 + tid;
    int row = c >> 3, ch = c & 7;
    ksrc[it] = Kb + (size_t)(b * S_ + row) * H_ + h * DK_ + ((ch ^ (row & 7)) << 3);
    int m = c >> 8, d = (c >> 2) & 63, pc = c & 3;
    int kc = pc ^ ((d >> 1) & 3);
    vsrc[it] = Vtb + (size_t)(b * H_ + h * DK_ + d) * S_ + m * 32 + kc * 8;
  }

  f32x4 ctx[4];   // ctx^T: col=q=lr, row d = nf*16 + 4*hi + j
#pragma unroll
  for (int nf = 0; nf < 4; ++nf) ctx[nf] = (f32x4){0.f, 0.f, 0.f, 0.f};
  float mrun = -30000.f, lrun = 0.f;

  for (int kv0 = 0; kv0 < S_; kv0 += 128) {
    __syncthreads();
#pragma unroll
    for (int it = 0; it < 4; ++it) {
      GLDS16(ksrc[it] + (size_t)kv0 * H_, Klds + (it * 256 + w * 64) * 8);
      GLDS16(vsrc[it] + kv0, Vtl + (it * 256 + w * 64) * 8);
    }
    __syncthreads();

    // swapped QK^T with interleaved key rows
    f32x4 sc[8];
#pragma unroll
    for (int m = 0; m < 4; ++m)
#pragma unroll
      for (int p = 0; p < 2; ++p) {
        int row = 32 * m + krow0 + 4 * p;
        int rb7 = (4 * p + (lr & 3));
        f32x4 acc = (f32x4){0.f, 0.f, 0.f, 0.f};
#pragma unroll
        for (int ks = 0; ks < 2; ++ks) {
          short8 kf = *(const short8*)((const char*)Klds + row * 128 +
                                       ((((ks << 2) | hi) ^ rb7) << 4));
          acc = __builtin_amdgcn_mfma_f32_16x16x32_bf16(kf, aq[ks], acc, 0, 0, 0);
        }
        sc[2 * m + p] = acc;
      }

    // online softmax for q=lr over 128 keys (32 in-reg + cross-hi shfl)
    f32x4 t0 = vmax4(vmax4(sc[0], sc[1]), vmax4(sc[2], sc[3]));
    f32x4 t1 = vmax4(vmax4(sc[4], sc[5]), vmax4(sc[6], sc[7]));
    f32x4 tt = vmax4(t0, t1);
    float mx = fmaxf(fmaxf(tt[0], tt[1]), fmaxf(tt[2], tt[3]));
    mx = fmaxf(mx, __shfl_xor(mx, 16));
    mx = fmaxf(mx, __shfl_xor(mx, 32));
    float mnew = fmaxf(mrun, mx);
    float scale = __expf(mrun - mnew);
    f32x4 s4 = (f32x4){0.f, 0.f, 0.f, 0.f};
#pragma unroll
    for (int n = 0; n < 8; ++n) {
#pragma unroll
      for (int j = 0; j < 4; ++j) sc[n][j] = __expf(sc[n][j] - mnew);
      s4 += sc[n];
    }
    float ps = (s4[0] + s4[1]) + (s4[2] + s4[3]);
    ps += __shfl_xor(ps, 16);
    ps += __shfl_xor(ps, 32);
    lrun = lrun * scale + ps;
    mrun = mnew;
#pragma unroll
    for (int nf = 0; nf < 4; ++nf) ctx[nf] *= scale;

    // PV: ctx^T += Vt_tile * P^T, all lane-local, 16x16x32 MFMA
#pragma unroll
    for (int m = 0; m < 4; ++m) {
      unsigned w0, w1, w2, w3;
      asm("v_cvt_pk_bf16_f32 %0, %1, %2" : "=v"(w0) : "v"(sc[2*m][0]), "v"(sc[2*m][1]));
      asm("v_cvt_pk_bf16_f32 %0, %1, %2" : "=v"(w1) : "v"(sc[2*m][2]), "v"(sc[2*m][3]));
      asm("v_cvt_pk_bf16_f32 %0, %1, %2" : "=v"(w2) : "v"(sc[2*m+1][0]), "v"(sc[2*m+1][1]));
      asm("v_cvt_pk_bf16_f32 %0, %1, %2" : "=v"(w3) : "v"(sc[2*m+1][2]), "v"(sc[2*m+1][3]));
      u32x4 wp; wp.x = w0; wp.y = w1; wp.z = w2; wp.w = w3;
      short8 pb = __builtin_bit_cast(short8, wp);
#pragma unroll
      for (int nf = 0; nf < 4; ++nf) {
        int d = 16 * nf + lr;
        short8 vt = *(const short8*)((const char*)Vtl + m * 4096 + d * 64 +
                                     ((hi ^ ((d >> 1) & 3)) << 4));
        ctx[nf] = __builtin_amdgcn_mfma_f32_16x16x32_bf16(vt, pb, ctx[nf], 0, 0, 0);
      }
    }
  }

  float inv = 1.0f / lrun;
  unsigned short* cp = Ctx + (size_t)(b * S_ + q0 + lr) * H_ + h * DK_;
#pragma unroll
  for (int nf = 0; nf < 4; ++nf) {
    ushort4 o;
    o.x = f2bf(ctx[nf][0] * inv);
    o.y = f2bf(ctx[nf][1] * inv);
    o.z = f2bf(ctx[nf][2] * inv);
    o.w = f2bf(ctx[nf][3] * inv);
    *(ushort4*)(cp + nf * 16 + hi * 4) = o;
  }
}

// ---------------- launch ----------------
extern "C" void kernel_launch(void* const* d_in, const int* in_sizes, int n_in,
                              void* d_out, int out_size, void* d_ws, size_t ws_size,
                              hipStream_t stream) {
  (void)in_sizes; (void)n_in; (void)out_size; (void)ws_size;
  const float* query = (const float*)d_in[0];
  const float* key   = (const float*)d_in[1];
  const float* value = (const float*)d_in[2];
  const int*   amask = (const int*)d_in[3];
  const float* Wq = (const float*)d_in[4];
  const float* bq = (const float*)d_in[5];
  const float* Wk = (const float*)d_in[6];
  const float* bk = (const float*)d_in[7];
  const float* Wv = (const float*)d_in[8];
  const float* bv = (const float*)d_in[9];
  const float* Wo = (const float*)d_in[10];
  const float* bo = (const float*)d_in[11];
  float* out = (float*)d_out;

  unsigned short* ws = (unsigned short*)d_ws;
  const size_t SZX = (size_t)M_ * H_;       // 4194304
  const size_t SZW = (size_t)H_ * H_;       // 1048576
  unsigned short* Xq  = ws;
  unsigned short* Xk  = Xq + SZX;
  unsigned short* Xv  = Xk + SZX;
  unsigned short* Wqb = Xv + SZX;
  unsigned short* Wkb = Wqb + SZW;
  unsigned short* Wvb = Wkb + SZW;
  unsigned short* Wob = Wvb + SZW;
  unsigned short* Qb  = Wob + SZW;
  unsigned short* Kb  = Qb + SZX;
  unsigned short* Vtb = Kb + SZX;
  unsigned short* Ctx = Vtb + SZX;

  k_cvt3<<<dim3(12288), dim3(256), 0, stream>>>(
      (const float4*)query, (const float4*)key, (const float4*)value,
      (ushort4*)Xq, (ushort4*)Xk, (ushort4*)Xv);
  k_cvtw<<<dim3(4096), dim3(256), 0, stream>>>(
      (const float4*)Wq, (const float4*)Wk, (const float4*)Wv, (const float4*)Wo,
      (ushort4*)Wqb, (ushort4*)Wkb, (ushort4*)Wvb, (ushort4*)Wob);
  k_gemm_qkv<<<dim3(8, 32, 3), dim3(256), 0, stream>>>(
      Xq, Xk, Xv, Wqb, Wkb, Wvb, bq, bk, bv, amask, Qb, Kb, Vtb);
  k_attn<<<dim3(1024), dim3(256), 0, stream>>>(Qb, Kb, Vtb, Ctx);
  k_gemm_o<<<dim3(8, 32), dim3(256), 0, stream>>>(Ctx, Wob, bo, out);
}

// Round 7
// 227.641 us; speedup vs baseline: 1.2894x; 1.0150x over previous
//
#include <hip/hip_runtime.h>
#include <stdint.h>

#define B_ 2
#define S_ 2048
#define H_ 1024
#define NH_ 16
#define DK_ 64
#define M_ (B_*S_)

typedef __attribute__((ext_vector_type(8))) short short8;
typedef __attribute__((ext_vector_type(4))) float f32x4;
typedef __attribute__((ext_vector_type(16))) float f32x16;
typedef __attribute__((ext_vector_type(4))) unsigned u32x4;

#define GLDS16(g, s) __builtin_amdgcn_global_load_lds( \
    (const __attribute__((address_space(1))) unsigned int*)(g), \
    (__attribute__((address_space(3))) unsigned int*)(s), 16, 0, 0)

__device__ __forceinline__ unsigned short f2bf(float x) {
  union { float f; unsigned u; } c; c.f = x;
  unsigned r = (c.u + 0x7FFF + ((c.u >> 16) & 1)) >> 16;
  return (unsigned short)r;
}

// ---------------- fp32 -> bf16 converts ----------------
__global__ void k_cvt3(const float4* __restrict__ a, const float4* __restrict__ b,
                       const float4* __restrict__ c,
                       ushort4* __restrict__ oa, ushort4* __restrict__ ob,
                       ushort4* __restrict__ oc) {
  int idx = blockIdx.x * 256 + threadIdx.x;      // 3 * 2^20
  int t = idx >> 20, i = idx & ((1 << 20) - 1);
  const float4* s = (t == 0) ? a : (t == 1) ? b : c;
  ushort4* o = (t == 0) ? oa : (t == 1) ? ob : oc;
  float4 v = s[i];
  ushort4 r; r.x = f2bf(v.x); r.y = f2bf(v.y); r.z = f2bf(v.z); r.w = f2bf(v.w);
  o[i] = r;
}

__global__ void k_cvtw(const float4* __restrict__ a, const float4* __restrict__ b,
                       const float4* __restrict__ c, const float4* __restrict__ d,
                       ushort4* __restrict__ oa, ushort4* __restrict__ ob,
                       ushort4* __restrict__ oc, ushort4* __restrict__ od) {
  int idx = blockIdx.x * 256 + threadIdx.x;      // 4 * 2^18
  int t = idx >> 18, i = idx & ((1 << 18) - 1);
  const float4* s = (t == 0) ? a : (t == 1) ? b : (t == 2) ? c : d;
  ushort4* o = (t == 0) ? oa : (t == 1) ? ob : (t == 2) ? oc : od;
  float4 v = s[i];
  ushort4 r; r.x = f2bf(v.x); r.y = f2bf(v.y); r.z = f2bf(v.z); r.w = f2bf(v.w);
  o[i] = r;
}

// ---------------- GEMM: C = A(MxK) * Bw(NxK)^T + bias, K=1024 ----------------
enum { MODE_Q = 0, MODE_K = 1, MODE_VT = 2, MODE_F32 = 3 };

__device__ __forceinline__ void gemm_body(
    const unsigned short* __restrict__ A, const unsigned short* __restrict__ Bw,
    const float* __restrict__ bias, const int* __restrict__ amask,
    void* __restrict__ Cout, int mode, int bx, int by) {
  __shared__ unsigned short As[128 * 64];   // [row][64], XOR-swizzled 16B chunks
  __shared__ unsigned short Bs[128 * 64];
  const int tid = threadIdx.x;
  const int w = tid >> 6, lane = tid & 63;
  const int lr = lane & 15, hi = lane >> 4;
  const int wr = w >> 1, wc = w & 1;
  const int m0 = by * 128, n0 = bx * 128;

  f32x4 acc[4][4];
#pragma unroll
  for (int i = 0; i < 4; i++)
#pragma unroll
    for (int j = 0; j < 4; j++) acc[i][j] = (f32x4){0.f, 0.f, 0.f, 0.f};

  for (int k0 = 0; k0 < H_; k0 += 64) {
    __syncthreads();
#pragma unroll
    for (int it = 0; it < 4; ++it) {
      int c = it * 256 + tid;
      int row = c >> 3, ch = c & 7;
      const unsigned short* ga = A + (size_t)(m0 + row) * H_ + k0 + ((ch ^ (row & 7)) << 3);
      GLDS16(ga, As + (it * 256 + w * 64) * 8);
      const unsigned short* gb = Bw + (size_t)(n0 + row) * H_ + k0 + ((ch ^ (row & 7)) << 3);
      GLDS16(gb, Bs + (it * 256 + w * 64) * 8);
    }
    __syncthreads();
#pragma unroll
    for (int ks = 0; ks < 2; ++ks) {
      short8 af[4], bfg[4];
#pragma unroll
      for (int mi = 0; mi < 4; ++mi) {
        int row = wr * 64 + mi * 16 + lr;
        int ch = ((ks << 2) | hi) ^ (lr & 7);
        af[mi] = *(const short8*)((const char*)As + row * 128 + (ch << 4));
      }
#pragma unroll
      for (int ni = 0; ni < 4; ++ni) {
        int row = wc * 64 + ni * 16 + lr;
        int ch = ((ks << 2) | hi) ^ (lr & 7);
        bfg[ni] = *(const short8*)((const char*)Bs + row * 128 + (ch << 4));
      }
#pragma unroll
      for (int mi = 0; mi < 4; ++mi)
#pragma unroll
        for (int ni = 0; ni < 4; ++ni)
          acc[mi][ni] = __builtin_amdgcn_mfma_f32_16x16x32_bf16(af[mi], bfg[ni], acc[mi][ni], 0, 0, 0);
    }
  }

  float bvv[4];
#pragma unroll
  for (int ni = 0; ni < 4; ++ni) bvv[ni] = bias[n0 + wc * 64 + ni * 16 + lr];

  if (mode == MODE_Q || mode == MODE_K) {
    unsigned short* C = (unsigned short*)Cout;
    float km[4][4];
    if (mode == MODE_K) {
#pragma unroll
      for (int mi = 0; mi < 4; ++mi)
#pragma unroll
        for (int j = 0; j < 4; ++j) {
          int r = m0 + wr * 64 + mi * 16 + hi * 4 + j;
          km[mi][j] = amask[r] ? 1.0f : 0.0f;
        }
    }
#pragma unroll
    for (int mi = 0; mi < 4; ++mi)
#pragma unroll
      for (int ni = 0; ni < 4; ++ni) {
        int col = n0 + wc * 64 + ni * 16 + lr;
#pragma unroll
        for (int j = 0; j < 4; ++j) {
          int r = m0 + wr * 64 + mi * 16 + hi * 4 + j;
          float v = acc[mi][ni][j] + bvv[ni];
          v *= (mode == MODE_Q) ? 0.125f : km[mi][j];
          C[(size_t)r * H_ + col] = f2bf(v);
        }
      }
  } else if (mode == MODE_F32) {
    float* C = (float*)Cout;
#pragma unroll
    for (int mi = 0; mi < 4; ++mi)
#pragma unroll
      for (int ni = 0; ni < 4; ++ni) {
        int col = n0 + wc * 64 + ni * 16 + lr;
#pragma unroll
        for (int j = 0; j < 4; ++j) {
          int r = m0 + wr * 64 + mi * 16 + hi * 4 + j;
          C[(size_t)r * H_ + col] = acc[mi][ni][j] + bvv[ni];
        }
      }
  } else {  // MODE_VT: Vt[(b*H + col)][s] = v, packed 4 bf16 along s
    unsigned short* Vt = (unsigned short*)Cout;
#pragma unroll
    for (int mi = 0; mi < 4; ++mi) {
      int rbase = m0 + wr * 64 + mi * 16 + hi * 4;
      int bb = rbase >> 11, s0 = rbase & (S_ - 1);
#pragma unroll
      for (int ni = 0; ni < 4; ++ni) {
        int col = n0 + wc * 64 + ni * 16 + lr;
        ushort4 pk;
        pk.x = f2bf(acc[mi][ni][0] + bvv[ni]);
        pk.y = f2bf(acc[mi][ni][1] + bvv[ni]);
        pk.z = f2bf(acc[mi][ni][2] + bvv[ni]);
        pk.w = f2bf(acc[mi][ni][3] + bvv[ni]);
        *(ushort4*)(Vt + (size_t)(bb * H_ + col) * S_ + s0) = pk;
      }
    }
  }
}

__global__ __launch_bounds__(256, 2) void k_gemm_qkv(
    const unsigned short* __restrict__ Xq, const unsigned short* __restrict__ Xk,
    const unsigned short* __restrict__ Xv,
    const unsigned short* __restrict__ Wqb, const unsigned short* __restrict__ Wkb,
    const unsigned short* __restrict__ Wvb,
    const float* __restrict__ bq, const float* __restrict__ bk,
    const float* __restrict__ bv, const int* __restrict__ amask,
    unsigned short* __restrict__ Qb, unsigned short* __restrict__ Kb,
    unsigned short* __restrict__ Vtb) {
  int z = blockIdx.z;
  const unsigned short* A = (z == 0) ? Xq : (z == 1) ? Xk : Xv;
  const unsigned short* W = (z == 0) ? Wqb : (z == 1) ? Wkb : Wvb;
  const float* bias = (z == 0) ? bq : (z == 1) ? bk : bv;
  void* C = (z == 0) ? (void*)Qb : (z == 1) ? (void*)Kb : (void*)Vtb;
  int mode = (z == 0) ? MODE_Q : (z == 1) ? MODE_K : MODE_VT;
  gemm_body(A, W, bias, amask, C, mode, blockIdx.x, blockIdx.y);
}

__global__ __launch_bounds__(256, 2) void k_gemm_o(
    const unsigned short* __restrict__ Ctx, const unsigned short* __restrict__ Wob,
    const float* __restrict__ bo, float* __restrict__ out) {
  gemm_body(Ctx, Wob, bo, nullptr, (void*)out, MODE_F32, blockIdx.x, blockIdx.y);
}

// ---------------- flash attention, 32x32x16 MFMA ----------------
// grid 512 blocks: (b, h, qtile of 128). 4 waves x 32 q-rows. KVBLK=64.
// Q pre-scaled 0.125; masked K rows zeroed (GEMM epilogues).
// K staged with key-permutation perm5 (swap bits 2<->3 within 32-key block):
// QK^T C-row r of sc[kb] then holds key 32kb + (r&3)+4*((r>>2)&1)+8*hi5+16*(r>>3),
// so lane (q=lane&31, hi5=lane>>5) holds exactly keys {16u+8*hi5+t} -- the
// 32x32x16 B-fragment layout (k=8*(lane>>5)+t) for PV. P stays in registers.
// All LDS reads chunk-swizzled ^(row&7): 8 lanes/bank-group = conflict floor.
__global__ __launch_bounds__(256, 2) void k_attn(
    const unsigned short* __restrict__ Qb, const unsigned short* __restrict__ Kb,
    const unsigned short* __restrict__ Vtb, unsigned short* __restrict__ Ctx) {
  __shared__ unsigned short Klds[64 * 64];   // [row][dk], row holds perm5'd key
  __shared__ unsigned short Vtl[64 * 64];    // [d][key]

  const int tid = threadIdx.x;
  const int w = tid >> 6, lane = tid & 63;
  const int l5 = lane & 31, hi5 = lane >> 5;
  int bid = (blockIdx.x & 7) * 64 + (blockIdx.x >> 3);  // XCD-chunked swizzle
  const int qt = bid & 15;
  const int h = (bid >> 4) & 15;
  const int b = bid >> 8;
  const int qr = qt * 128 + w * 32 + l5;   // this lane's q row (col of C)

  // Q fragment (B operand): col=q=l5, k = dkblk*16 + 8*hi5 + t
  short8 aq[4];
  {
    const unsigned short* qp = Qb + (size_t)(b * S_ + qr) * H_ + h * DK_ + hi5 * 8;
#pragma unroll
    for (int dkblk = 0; dkblk < 4; ++dkblk)
      aq[dkblk] = *(const short8*)(qp + dkblk * 16);
  }

  // staging source pointers (2 K chunks + 2 Vt chunks per thread per tile)
  const unsigned short* ksrc[2];
  const unsigned short* vsrc[2];
#pragma unroll
  for (int it = 0; it < 2; ++it) {
    int c = it * 256 + tid;
    int rho = c >> 3, cl = c & 7;
    int kap = 32 * (rho >> 5) + ((rho & 19) | ((rho & 4) << 1) | ((rho & 8) >> 1));
    ksrc[it] = Kb + (size_t)(b * S_ + kap) * H_ + h * DK_ + ((cl ^ (rho & 7)) << 3);
    vsrc[it] = Vtb + (size_t)(b * H_ + h * DK_ + rho) * S_ + ((cl ^ (rho & 7)) << 3);
  }

  f32x16 ctx[2];
#pragma unroll
  for (int dblk = 0; dblk < 2; ++dblk)
#pragma unroll
    for (int i = 0; i < 16; ++i) ctx[dblk][i] = 0.f;
  float mrun = -30000.f, lrun = 0.f;

  for (int kv0 = 0; kv0 < S_; kv0 += 64) {
    __syncthreads();
#pragma unroll
    for (int it = 0; it < 2; ++it) {
      GLDS16(ksrc[it] + (size_t)kv0 * H_, Klds + (it * 256 + w * 64) * 8);
      GLDS16(vsrc[it] + kv0, Vtl + (it * 256 + w * 64) * 8);
    }
    __syncthreads();

    // QK^T: sc[kb] = St over 32 keys x 32 q, A=K rows (perm5'd), B=Q
    f32x16 sc[2];
#pragma unroll
    for (int kb = 0; kb < 2; ++kb) {
      f32x16 a;
#pragma unroll
      for (int i = 0; i < 16; ++i) a[i] = 0.f;
#pragma unroll
      for (int dkblk = 0; dkblk < 4; ++dkblk) {
        int row = kb * 32 + l5;
        int ch = (2 * dkblk + hi5) ^ (row & 7);
        short8 kf = *(const short8*)((const char*)Klds + row * 128 + (ch << 4));
        a = __builtin_amdgcn_mfma_f32_32x32x16_bf16(kf, aq[dkblk], a, 0, 0, 0);
      }
      sc[kb] = a;
    }

    // online softmax: lane's 32 values + one cross-half shfl
    float mx = sc[0][0];
#pragma unroll
    for (int i = 1; i < 16; ++i) mx = fmaxf(mx, sc[0][i]);
#pragma unroll
    for (int i = 0; i < 16; ++i) mx = fmaxf(mx, sc[1][i]);
    mx = fmaxf(mx, __shfl_xor(mx, 32));
    float mnew = fmaxf(mrun, mx);
    float scale = __expf(mrun - mnew);
    float ps = 0.f;
#pragma unroll
    for (int kb = 0; kb < 2; ++kb)
#pragma unroll
      for (int i = 0; i < 16; ++i) {
        float e = __expf(sc[kb][i] - mnew);
        sc[kb][i] = e;
        ps += e;
      }
    ps += __shfl_xor(ps, 32);
    lrun = lrun * scale + ps;
    mrun = mnew;
#pragma unroll
    for (int dblk = 0; dblk < 2; ++dblk)
#pragma unroll
      for (int i = 0; i < 16; ++i) ctx[dblk][i] *= scale;

    // PV: ctx^T += Vt * P^T ; P^T fragment is lane-local (keys 16u+8*hi5+t)
#pragma unroll
    for (int kb = 0; kb < 2; ++kb)
#pragma unroll
      for (int u = 0; u < 2; ++u) {
        unsigned w0, w1, w2, w3;
        asm("v_cvt_pk_bf16_f32 %0, %1, %2" : "=v"(w0) : "v"(sc[kb][8*u+0]), "v"(sc[kb][8*u+1]));
        asm("v_cvt_pk_bf16_f32 %0, %1, %2" : "=v"(w1) : "v"(sc[kb][8*u+2]), "v"(sc[kb][8*u+3]));
        asm("v_cvt_pk_bf16_f32 %0, %1, %2" : "=v"(w2) : "v"(sc[kb][8*u+4]), "v"(sc[kb][8*u+5]));
        asm("v_cvt_pk_bf16_f32 %0, %1, %2" : "=v"(w3) : "v"(sc[kb][8*u+6]), "v"(sc[kb][8*u+7]));
        u32x4 wp; wp.x = w0; wp.y = w1; wp.z = w2; wp.w = w3;
        short8 pb = __builtin_bit_cast(short8, wp);
#pragma unroll
        for (int dblk = 0; dblk < 2; ++dblk) {
          int row = dblk * 32 + l5;
          int ch = (4 * kb + 2 * u + hi5) ^ (row & 7);
          short8 vt = *(const short8*)((const char*)Vtl + row * 128 + (ch << 4));
          ctx[dblk] = __builtin_amdgcn_mfma_f32_32x32x16_bf16(vt, pb, ctx[dblk], 0, 0, 0);
        }
      }
  }

  float inv = 1.0f / lrun;
  unsigned short* cp = Ctx + (size_t)(b * S_ + qr) * H_ + h * DK_;
#pragma unroll
  for (int dblk = 0; dblk < 2; ++dblk)
#pragma unroll
    for (int s = 0; s < 4; ++s) {
      ushort4 o;
      o.x = f2bf(ctx[dblk][4*s+0] * inv);
      o.y = f2bf(ctx[dblk][4*s+1] * inv);
      o.z = f2bf(ctx[dblk][4*s+2] * inv);
      o.w = f2bf(ctx[dblk][4*s+3] * inv);
      *(ushort4*)(cp + dblk * 32 + 8 * s + 4 * hi5) = o;
    }
}

// ---------------- launch ----------------
extern "C" void kernel_launch(void* const* d_in, const int* in_sizes, int n_in,
                              void* d_out, int out_size, void* d_ws, size_t ws_size,
                              hipStream_t stream) {
  (void)in_sizes; (void)n_in; (void)out_size; (void)ws_size;
  const float* query = (const float*)d_in[0];
  const float* key   = (const float*)d_in[1];
  const float* value = (const float*)d_in[2];
  const int*   amask = (const int*)d_in[3];
  const float* Wq = (const float*)d_in[4];
  const float* bq = (const float*)d_in[5];
  const float* Wk = (const float*)d_in[6];
  const float* bk = (const float*)d_in[7];
  const float* Wv = (const float*)d_in[8];
  const float* bv = (const float*)d_in[9];
  const float* Wo = (const float*)d_in[10];
  const float* bo = (const float*)d_in[11];
  float* out = (float*)d_out;

  unsigned short* ws = (unsigned short*)d_ws;
  const size_t SZX = (size_t)M_ * H_;       // 4194304
  const size_t SZW = (size_t)H_ * H_;       // 1048576
  unsigned short* Xq  = ws;
  unsigned short* Xk  = Xq + SZX;
  unsigned short* Xv  = Xk + SZX;
  unsigned short* Wqb = Xv + SZX;
  unsigned short* Wkb = Wqb + SZW;
  unsigned short* Wvb = Wkb + SZW;
  unsigned short* Wob = Wvb + SZW;
  unsigned short* Qb  = Wob + SZW;
  unsigned short* Kb  = Qb + SZX;
  unsigned short* Vtb = Kb + SZX;
  unsigned short* Ctx = Vtb + SZX;

  k_cvt3<<<dim3(12288), dim3(256), 0, stream>>>(
      (const float4*)query, (const float4*)key, (const float4*)value,
      (ushort4*)Xq, (ushort4*)Xk, (ushort4*)Xv);
  k_cvtw<<<dim3(4096), dim3(256), 0, stream>>>(
      (const float4*)Wq, (const float4*)Wk, (const float4*)Wv, (const float4*)Wo,
      (ushort4*)Wqb, (ushort4*)Wkb, (ushort4*)Wvb, (ushort4*)Wob);
  k_gemm_qkv<<<dim3(8, 32, 3), dim3(256), 0, stream>>>(
      Xq, Xk, Xv, Wqb, Wkb, Wvb, bq, bk, bv, amask, Qb, Kb, Vtb);
  k_attn<<<dim3(512), dim3(256), 0, stream>>>(Qb, Kb, Vtb, Ctx);
  k_gemm_o<<<dim3(8, 32), dim3(256), 0, stream>>>(Ctx, Wob, bo, out);
}